// Round 2
// baseline (99.230 us; speedup 1.0000x reference)
//
#include <hip/hip_runtime.h>

#define B_DIM   128
#define N_IN    16384
#define N_OUT   8192
#define N_EDGES (N_OUT * 64)

#define WAVES_PB 8                  // waves per block = outputs per block
#define J_BLK    WAVES_PB
#define THREADS  (WAVES_PB * 64)    // 512
#define CHUNK    64                 // edges staged per wave per iteration

__device__ __forceinline__ int lower_bound_dev(const int* __restrict__ a, int n, int v) {
    int lo = 0, hi = n;
    while (lo < hi) {
        int mid = (lo + hi) >> 1;
        if (a[mid] < v) lo = mid + 1; else hi = mid;
    }
    return lo;
}

// rp[j] = first edge index with dst >= j (j in [0, N_OUT]), via boundary scatter.
// dst is sorted ascending. Coalesced reads, one small write per distinct dst value.
__global__ void build_rowptr_kernel(const int* __restrict__ dst, int* __restrict__ rp) {
    const int e = blockIdx.x * blockDim.x + threadIdx.x;
    if (e >= N_EDGES) return;
    const int d     = dst[e];
    const int dprev = (e == 0) ? -1 : dst[e - 1];
    for (int j = dprev + 1; j <= d; ++j) rp[j] = e;
    if (e == N_EDGES - 1)
        for (int j = d + 1; j <= N_OUT; ++j) rp[j] = N_EDGES;
}

// x[B][N_IN] -> xT[N_IN][B], 32x32 LDS tiles, both sides coalesced
__global__ __launch_bounds__(256) void transpose_kernel(const float* __restrict__ x,
                                                        float* __restrict__ xT) {
    __shared__ float tile[32][33];
    const int i0 = blockIdx.x * 32;   // N_IN dim
    const int b0 = blockIdx.y * 32;   // B dim
    const int tx = threadIdx.x;       // 0..31
    const int ty = threadIdx.y;       // 0..7
#pragma unroll
    for (int r = 0; r < 32; r += 8)
        tile[ty + r][tx] = x[(size_t)(b0 + ty + r) * N_IN + (i0 + tx)];
    __syncthreads();
#pragma unroll
    for (int r = 0; r < 32; r += 8)
        xT[(size_t)(i0 + ty + r) * B_DIM + (b0 + tx)] = tile[tx][ty + r];
}

// One WAVE per output unit. Lane l accumulates batch elements (2l, 2l+1) via a
// single float2 gather per edge (one full 512B xT row per wave-instruction).
// Edge metadata (src,w) staged cooperatively into LDS per 64-edge chunk.
template <bool TRANSPOSED, bool USE_RP>
__global__ __launch_bounds__(THREADS) void sparse_layer_kernel(
        const float* __restrict__ xg, const float* __restrict__ w,
        const float* __restrict__ bias, const int* __restrict__ src,
        const int* __restrict__ dst, const int* __restrict__ rp,
        float* __restrict__ y) {
    __shared__ int   s_src[J_BLK][CHUNK];
    __shared__ float s_w[J_BLK][CHUNK];
    __shared__ float tile[J_BLK][132];   // pad: float2 writes -> 2-way alias (free)
    __shared__ int   srp[J_BLK + 1];

    const int tid  = threadIdx.x;
    const int wid  = tid >> 6;           // wave id = local output index
    const int lane = tid & 63;
    const int j0   = blockIdx.x * J_BLK;
    const int j    = j0 + wid;

    if (!USE_RP) {
        if (tid <= J_BLK) srp[tid] = lower_bound_dev(dst, N_EDGES, j0 + tid);
        __syncthreads();
    }

    int e0, e1;
    if (USE_RP) { e0 = rp[j]; e1 = rp[j + 1]; }
    else        { e0 = srp[wid]; e1 = srp[wid + 1]; }

    float acc0 = 0.f, acc1 = 0.f;
    const int b0 = lane * 2;
    // Pre-offset row pointer: row s for this lane = xrow[s * (B_DIM/2)]
    const float2* xrow = (const float2*)xg + lane;

    for (int base = e0; base < e1; base += CHUNK) {
        const int n = min(CHUNK, e1 - base);
        if (lane < n) {
            s_src[wid][lane] = src[base + lane];
            s_w[wid][lane]   = w[base + lane];
        }
        __builtin_amdgcn_wave_barrier();   // order LDS write -> read within wave
#pragma unroll 4
        for (int k = 0; k < n; ++k) {
            const int   s  = s_src[wid][k];
            const float wt = s_w[wid][k];
            if (TRANSPOSED) {
                const float2 v = xrow[(size_t)s * (B_DIM / 2)];
                acc0 = fmaf(v.x, wt, acc0);
                acc1 = fmaf(v.y, wt, acc1);
            } else {
                acc0 = fmaf(xg[(size_t)b0 * N_IN + s],       wt, acc0);
                acc1 = fmaf(xg[(size_t)(b0 + 1) * N_IN + s], wt, acc1);
            }
        }
        __builtin_amdgcn_wave_barrier();   // don't overwrite LDS before reads done
    }

    tile[wid][b0]     = acc0;
    tile[wid][b0 + 1] = acc1;
    __syncthreads();

    // Coalesced epilogue: 8 consecutive lanes write 8 consecutive j (32B segment).
#pragma unroll
    for (int i = tid; i < B_DIM * J_BLK; i += THREADS) {
        const int bb = i >> 3;
        const int jj = i & (J_BLK - 1);
        const float v = tile[jj][bb] + bias[j0 + jj];
        y[(size_t)bb * N_OUT + (j0 + jj)] = fmaxf(v, 0.f);
    }
}

extern "C" void kernel_launch(void* const* d_in, const int* in_sizes, int n_in,
                              void* d_out, int out_size, void* d_ws, size_t ws_size,
                              hipStream_t stream) {
    const float* x    = (const float*)d_in[0];
    const float* w    = (const float*)d_in[1];
    const float* bias = (const float*)d_in[2];
    const int*   esrc = (const int*)d_in[3];
    const int*   edst = (const int*)d_in[4];
    float*       y    = (float*)d_out;

    const size_t RP_BYTES = (size_t)(N_OUT + 1) * sizeof(int);
    const size_t XT_OFF   = 65536;  // rp at offset 0, xT at 64KB
    const size_t XT_BYTES = (size_t)N_IN * B_DIM * sizeof(float);

    const bool has_rp = ws_size >= RP_BYTES;
    const bool has_xt = ws_size >= XT_OFF + XT_BYTES;

    int*   rp = (int*)d_ws;
    float* xT = (float*)((char*)d_ws + XT_OFF);

    if (has_rp) {
        build_rowptr_kernel<<<(N_EDGES + 255) / 256, 256, 0, stream>>>(edst, rp);
    }
    if (has_xt) {
        transpose_kernel<<<dim3(N_IN / 32, B_DIM / 32), dim3(32, 8), 0, stream>>>(x, xT);
    }

    dim3 grid(N_OUT / J_BLK);   // 1024 blocks -> 4 blocks/CU, 32 waves/CU
    if (has_xt) {
        sparse_layer_kernel<true,  true ><<<grid, THREADS, 0, stream>>>(xT, w, bias, esrc, edst, rp, y);
    } else if (has_rp) {
        sparse_layer_kernel<false, true ><<<grid, THREADS, 0, stream>>>(x,  w, bias, esrc, edst, rp, y);
    } else {
        sparse_layer_kernel<false, false><<<grid, THREADS, 0, stream>>>(x,  w, bias, esrc, edst, rp, y);
    }
}

// Round 3
// 98.809 us; speedup vs baseline: 1.0043x; 1.0043x over previous
//
#include <hip/hip_runtime.h>

#define B_DIM   128
#define N_IN    16384
#define N_OUT   8192
#define N_EDGES (N_OUT * 64)

#define WAVES_PB 8                  // waves per block = outputs per block
#define J_BLK    WAVES_PB
#define THREADS  (WAVES_PB * 64)    // 512

__device__ __forceinline__ int lower_bound_dev(const int* __restrict__ a, int n, int v) {
    int lo = 0, hi = n;
    while (lo < hi) {
        int mid = (lo + hi) >> 1;
        if (a[mid] < v) lo = mid + 1; else hi = mid;
    }
    return lo;
}

// rp[j] = first edge index with dst >= j (j in [0, N_OUT]), via boundary scatter.
__global__ void build_rowptr_kernel(const int* __restrict__ dst, int* __restrict__ rp) {
    const int e = blockIdx.x * blockDim.x + threadIdx.x;
    if (e >= N_EDGES) return;
    const int d     = dst[e];
    const int dprev = (e == 0) ? -1 : dst[e - 1];
    for (int j = dprev + 1; j <= d; ++j) rp[j] = e;
    if (e == N_EDGES - 1)
        for (int j = d + 1; j <= N_OUT; ++j) rp[j] = N_EDGES;
}

// x[B][N_IN] -> xT[N_IN][B], 32x32 LDS tiles, both sides coalesced
__global__ __launch_bounds__(256) void transpose_kernel(const float* __restrict__ x,
                                                        float* __restrict__ xT) {
    __shared__ float tile[32][33];
    const int i0 = blockIdx.x * 32;
    const int b0 = blockIdx.y * 32;
    const int tx = threadIdx.x;
    const int ty = threadIdx.y;
#pragma unroll
    for (int r = 0; r < 32; r += 8)
        tile[ty + r][tx] = x[(size_t)(b0 + ty + r) * N_IN + (i0 + tx)];
    __syncthreads();
#pragma unroll
    for (int r = 0; r < 32; r += 8)
        xT[(size_t)(i0 + ty + r) * B_DIM + (b0 + tx)] = tile[tx][ty + r];
}

// One WAVE per output. Half-wave h (=lane>>5) services edge e+h of each pair;
// lane covers batch cols bcol..bcol+3 via one float4 gather (full 512B xT row
// per half-wave instruction). Edge metadata is read on the SCALAR pipe
// (uniform index via readfirstlane -> s_load), no LDS staging, no per-lane
// metadata loads. Cross-half reduce at the end via shfl_xor(32).
__global__ __launch_bounds__(THREADS, 8) void sparse_layer_fast(
        const float* __restrict__ xT, const float* __restrict__ w,
        const float* __restrict__ bias, const int* __restrict__ src,
        const int* __restrict__ rp, float* __restrict__ y) {
    __shared__ float tile[J_BLK][132];

    const int tid  = threadIdx.x;
    const int wid  = tid >> 6;
    const int lane = tid & 63;
    const int half = lane >> 5;
    const int bcol = (lane & 31) << 2;
    const int j0   = blockIdx.x * J_BLK;
    const int j    = j0 + wid;

    const int e0 = __builtin_amdgcn_readfirstlane(rp[j]);
    const int e1 = __builtin_amdgcn_readfirstlane(rp[j + 1]);

    float4 acc = {0.f, 0.f, 0.f, 0.f};
    const float4* xrow = (const float4*)xT + (bcol >> 2);

    int e = e0;
    // Main loop: 8 edges (4 pairs) per iteration; scalar metadata, 4 gathers in flight.
    for (; e + 8 <= e1; e += 8) {
#pragma unroll
        for (int p = 0; p < 4; ++p) {
            const int   ea = e + 2 * p;
            const int   sa = src[ea];
            const int   sb = src[ea + 1];
            const float wa = w[ea];
            const float wb = w[ea + 1];
            const int   s  = half ? sb : sa;
            const float wt = half ? wb : wa;
            const float4 v = xrow[(size_t)s * (B_DIM / 4)];
            acc.x = fmaf(v.x, wt, acc.x);
            acc.y = fmaf(v.y, wt, acc.y);
            acc.z = fmaf(v.z, wt, acc.z);
            acc.w = fmaf(v.w, wt, acc.w);
        }
    }
    // Tail: pairs, with odd-edge handling (half 1 gets zero weight).
    for (; e < e1; e += 2) {
        const int   sa    = src[e];
        const float wa    = w[e];
        const bool  has_b = (e + 1) < e1;
        const int   sb    = has_b ? src[e + 1] : sa;
        const float wb    = has_b ? w[e + 1] : 0.f;
        const int   s     = half ? sb : sa;
        const float wt    = half ? wb : wa;
        const float4 v = xrow[(size_t)s * (B_DIM / 4)];
        acc.x = fmaf(v.x, wt, acc.x);
        acc.y = fmaf(v.y, wt, acc.y);
        acc.z = fmaf(v.z, wt, acc.z);
        acc.w = fmaf(v.w, wt, acc.w);
    }

    // Combine the two half-wave partial sums (lane l and l^32 share a b-range).
    acc.x += __shfl_xor(acc.x, 32, 64);
    acc.y += __shfl_xor(acc.y, 32, 64);
    acc.z += __shfl_xor(acc.z, 32, 64);
    acc.w += __shfl_xor(acc.w, 32, 64);

    if (half == 0) {
        *(float4*)&tile[wid][bcol] = acc;   // row stride 132*4=528B (16B-aligned)
    }
    __syncthreads();

    // Coalesced epilogue: 8 consecutive lanes write 8 consecutive j (32B segment).
#pragma unroll
    for (int i = tid; i < B_DIM * J_BLK; i += THREADS) {
        const int bb = i >> 3;
        const int jj = i & (J_BLK - 1);
        const float v = tile[jj][bb] + bias[j0 + jj];
        y[(size_t)bb * N_OUT + (j0 + jj)] = fmaxf(v, 0.f);
    }
}

// Fallback (no usable workspace): per-output wave, gathers from row-major x.
__global__ __launch_bounds__(THREADS) void sparse_layer_fallback(
        const float* __restrict__ x, const float* __restrict__ w,
        const float* __restrict__ bias, const int* __restrict__ src,
        const int* __restrict__ dst, float* __restrict__ y) {
    __shared__ float tile[J_BLK][130];
    __shared__ int   srp[J_BLK + 1];

    const int tid  = threadIdx.x;
    const int wid  = tid >> 6;
    const int lane = tid & 63;
    const int j0   = blockIdx.x * J_BLK;

    if (tid <= J_BLK) srp[tid] = lower_bound_dev(dst, N_EDGES, j0 + tid);
    __syncthreads();

    const int e0 = srp[wid], e1 = srp[wid + 1];
    const int b0 = lane * 2;
    float acc0 = 0.f, acc1 = 0.f;
    for (int e = e0; e < e1; ++e) {
        const int   s  = src[e];
        const float wt = w[e];
        acc0 = fmaf(x[(size_t)b0 * N_IN + s], wt, acc0);
        acc1 = fmaf(x[(size_t)(b0 + 1) * N_IN + s], wt, acc1);
    }
    tile[wid][b0]     = acc0;
    tile[wid][b0 + 1] = acc1;
    __syncthreads();
#pragma unroll
    for (int i = tid; i < B_DIM * J_BLK; i += THREADS) {
        const int bb = i >> 3;
        const int jj = i & (J_BLK - 1);
        const float v = tile[jj][bb] + bias[j0 + jj];
        y[(size_t)bb * N_OUT + (j0 + jj)] = fmaxf(v, 0.f);
    }
}

extern "C" void kernel_launch(void* const* d_in, const int* in_sizes, int n_in,
                              void* d_out, int out_size, void* d_ws, size_t ws_size,
                              hipStream_t stream) {
    const float* x    = (const float*)d_in[0];
    const float* w    = (const float*)d_in[1];
    const float* bias = (const float*)d_in[2];
    const int*   esrc = (const int*)d_in[3];
    const int*   edst = (const int*)d_in[4];
    float*       y    = (float*)d_out;

    const size_t RP_BYTES = (size_t)(N_OUT + 1) * sizeof(int);
    const size_t XT_OFF   = 65536;
    const size_t XT_BYTES = (size_t)N_IN * B_DIM * sizeof(float);

    const bool has_ws = ws_size >= XT_OFF + XT_BYTES && ws_size >= RP_BYTES;

    int*   rp = (int*)d_ws;
    float* xT = (float*)((char*)d_ws + XT_OFF);

    if (has_ws) {
        build_rowptr_kernel<<<(N_EDGES + 255) / 256, 256, 0, stream>>>(edst, rp);
        transpose_kernel<<<dim3(N_IN / 32, B_DIM / 32), dim3(32, 8), 0, stream>>>(x, xT);
        sparse_layer_fast<<<dim3(N_OUT / J_BLK), THREADS, 0, stream>>>(xT, w, bias, esrc, rp, y);
    } else {
        sparse_layer_fallback<<<dim3(N_OUT / J_BLK), THREADS, 0, stream>>>(x, w, bias, esrc, edst, y);
    }
}